// Round 15
// baseline (26.029 us; speedup 1.0000x reference)
//
#include <hip/hip_runtime.h>

// MPO/TT embedding: out[t] = A2[h(t)] (16x64) . B3[l(t)] (64x48), MFMA edition.
// cores: c0 (1,8,4,32) c1 (32,8,4,64) c2 (64,8,4,64) c3 (64,8,4,24) c4 (24,8,3,1)
// v = token id; h = v>>9 (i1=h>>3,i2=h&7); l = v&511 (i3=l>>6, l2=l&63, i4=l2>>3, i5=l2&7)
// o = o12*48 + o345 ; o12 = o1*4+o2 (16, =M) ; o345 = o3*12+o4*3+o5 (48, =N); r2 = K (64)
//
// R15: R14 + padded-B4s LDS layout. B4s[r3][g][4] (g = o45-triplet group = o4):
// staging thread (r3, m=o4) writes its triplet contiguously at [r3*16+m*4+c];
// consumer reads ONE aligned float4 per (r3,g) -> 64 ds_read_b128 (broadcast,
// conflict-free) instead of 192 ds_read_b32 per wave. Bit-identical values.
//
// Fragment layouts (R13/R14-validated on HW):
//   A-frag: lane = lh*16+m holds k = ks*32+lh*8+j, j=0..7
//   B-frag: lane = lh*16+n, same k packing
//   A2Tb[h][ks][lane][j] : 128 KB ; B3pb[l][nt][ks][lane][j] : 3 MB
//   C/D: col(n) = lane&15, row(m) = (lane>>4)*4+reg

typedef __attribute__((ext_vector_type(8))) short bf16x8;
typedef __attribute__((ext_vector_type(8))) unsigned short u16x8;
typedef __attribute__((ext_vector_type(4))) float f32x4;

__device__ __forceinline__ unsigned short f2bf(float x) {
    unsigned u = __float_as_uint(x);
    unsigned r = (u + 0x7FFFu + ((u >> 16) & 1u)) >> 16;   // RNE
    return (unsigned short)r;
}

// ---- prep: 2048 B3 quarter-blocks + 64 A2T blocks ----
__global__ __launch_bounds__(256) void k_prep(const float* __restrict__ c0,
                                              const float* __restrict__ c1,
                                              const float* __restrict__ c2,
                                              const float* __restrict__ c3,
                                              const float* __restrict__ c4,
                                              unsigned short* __restrict__ A2Tb,
                                              unsigned short* __restrict__ B3pb) {
    const int t = threadIdx.x;
    const int b = blockIdx.x;

    if (b >= 2048) {
        // ---- A2 for h = b-2048, packed as A-fragments ----
        if (t >= 128) return;
        int h = b - 2048;
        int i1 = h >> 3, i2 = h & 7;
        int m = t & 15, kc = t >> 4;            // kc in 0..7 ; r2 = kc*8 + j
        int o1 = m >> 2, o2 = m & 3;
        const float* c0r = c0 + i1 * 128 + o1 * 32;          // [i1][o1][r1]
        const float* c1p = c1 + i2 * 256 + o2 * 64 + kc * 8; // + r1*2048
        float s[8] = {};
#pragma unroll
        for (int r1 = 0; r1 < 32; ++r1) {
            float a = c0r[r1];
            float4 v0 = *reinterpret_cast<const float4*>(c1p + r1 * 2048);
            float4 v1 = *reinterpret_cast<const float4*>(c1p + r1 * 2048 + 4);
            s[0] += a * v0.x; s[1] += a * v0.y; s[2] += a * v0.z; s[3] += a * v0.w;
            s[4] += a * v1.x; s[5] += a * v1.y; s[6] += a * v1.z; s[7] += a * v1.w;
        }
        int ks = kc >> 2, lh = kc & 3;          // lane = lh*16 + m
        unsigned short* dst = A2Tb + (size_t)(((h * 2 + ks) * 64 + lh * 16 + m)) * 8;
        *reinterpret_cast<ushort4*>(dst) =
            make_ushort4(f2bf(s[0]), f2bf(s[1]), f2bf(s[2]), f2bf(s[3]));
        *reinterpret_cast<ushort4*>(dst + 4) =
            make_ushort4(f2bf(s[4]), f2bf(s[5]), f2bf(s[6]), f2bf(s[7]));
        return;
    }

    // ---- B3 quarter: l = b>>2, r2 in [16p, 16p+16) ----
    const int l = b >> 2, p = b & 3;
    const int i3 = l >> 6, l2 = l & 63;
    const int i4 = l2 >> 3, i5 = l2 & 7;
    const int ks = p >> 1, lh0 = (p & 1) * 2;   // this quarter's K-step / lane-half base

    __shared__ float B4s[64 * 16];        // [r3][g=o4][4] padded (4 KB)
    __shared__ unsigned short stg[768];   // [nt][lhrel][n][j] = [3][2][16][8]

    {
        int r3 = t >> 2, m = t & 3;  // m = o4 = triplet group g
        const float* c3p = c3 + r3 * 768 + i4 * 96 + m * 24;
        const float* c4p = c4 + i5 * 3;
        float a0 = 0.f, a1 = 0.f, a2 = 0.f;
#pragma unroll
        for (int r4q = 0; r4q < 24; r4q += 4) {
            float4 cv = *reinterpret_cast<const float4*>(c3p + r4q);
            float cc[4] = {cv.x, cv.y, cv.z, cv.w};
#pragma unroll
            for (int d = 0; d < 4; ++d) {
                const float* bb = c4p + (r4q + d) * 24;
                a0 += cc[d] * bb[0];
                a1 += cc[d] * bb[1];
                a2 += cc[d] * bb[2];
            }
        }
        // padded layout: o45 = 3m+c -> group g = m, elem e = c
        float* o = B4s + r3 * 16 + m * 4;
        o[0] = a0; o[1] = a1; o[2] = a2;   // [3] unused
    }
    __syncthreads();

    {
        int r2l = t >> 4;                 // 0..15 within quarter; r2 = 16p + r2l
        int jj = t & 15;
        int r2 = 16 * p + r2l;
        int lhrel = r2l >> 3, j = r2l & 7;
        int o3 = jj >> 2, g = jj & 3;
        const float* c2p = c2 + r2 * 2048 + i3 * 256 + o3 * 64;  // + r3
        const float* b4g = B4s + g * 4;                          // + r3*16
        float a0 = 0.f, a1 = 0.f, a2 = 0.f;
#pragma unroll
        for (int r3q = 0; r3q < 64; r3q += 4) {
            float4 cv = *reinterpret_cast<const float4*>(c2p + r3q);
            float cc[4] = {cv.x, cv.y, cv.z, cv.w};
#pragma unroll
            for (int d = 0; d < 4; ++d) {
                float4 bv = *reinterpret_cast<const float4*>(b4g + (r3q + d) * 16);
                a0 += cc[d] * bv.x;
                a1 += cc[d] * bv.y;
                a2 += cc[d] * bv.z;
            }
        }
        // stage in fragment order (LDS), then coalesced global write below
        float av[3] = {a0, a1, a2};
#pragma unroll
        for (int c = 0; c < 3; ++c) {
            int o345 = 3 * jj + c;
            int nt = o345 >> 4, n = o345 & 15;
            stg[nt * 256 + lhrel * 128 + n * 8 + j] = f2bf(av[c]);
        }
    }
    __syncthreads();

    if (t < 96) {
        // local linear u16 index = t*8 ; global = l*3072 + (nt*2+ks)*512 + lh0*128 + r
        int nt = t >> 5, r = (t & 31) * 8;
        u16x8 val = *reinterpret_cast<const u16x8*>(stg + t * 8);
        size_t dst = (size_t)l * 3072 + (size_t)(nt * 2 + ks) * 512 + lh0 * 128 + r;
        *reinterpret_cast<u16x8*>(B3pb + dst) = val;
    }
}

// ---- main: one wave per token, 6 MFMA (unchanged from R13/R14) ----
__global__ __launch_bounds__(256) void k_main(const int* __restrict__ ids,
                                              const unsigned short* __restrict__ A2Tb,
                                              const unsigned short* __restrict__ B3pb,
                                              float* __restrict__ out,
                                              int n_tokens) {
    const int t = threadIdx.x;
    const int wave = t >> 6, lane = t & 63;
    const int token = blockIdx.x * 4 + wave;
    if (token >= n_tokens) return;

    const int v = ids[token];
    const int h = v >> 9, l = v & 511;

    const bf16x8* A = reinterpret_cast<const bf16x8*>(A2Tb) + h * 128 + lane;
    const bf16x8* B = reinterpret_cast<const bf16x8*>(B3pb) + l * 384 + lane;

    bf16x8 a0 = A[0];
    bf16x8 a1 = A[64];
    f32x4 z = {0.f, 0.f, 0.f, 0.f};

    f32x4 acc0 = __builtin_amdgcn_mfma_f32_16x16x32_bf16(a0, B[0],   z, 0, 0, 0);
    acc0       = __builtin_amdgcn_mfma_f32_16x16x32_bf16(a1, B[64],  acc0, 0, 0, 0);
    f32x4 acc1 = __builtin_amdgcn_mfma_f32_16x16x32_bf16(a0, B[128], z, 0, 0, 0);
    acc1       = __builtin_amdgcn_mfma_f32_16x16x32_bf16(a1, B[192], acc1, 0, 0, 0);
    f32x4 acc2 = __builtin_amdgcn_mfma_f32_16x16x32_bf16(a0, B[256], z, 0, 0, 0);
    acc2       = __builtin_amdgcn_mfma_f32_16x16x32_bf16(a1, B[320], acc2, 0, 0, 0);

    // C/D: col = lane&15 (n within tile), row = (lane>>4)*4 + reg (= o12)
    const int n = lane & 15;
    float* o = out + (size_t)token * 768 + ((lane >> 4) * 4) * 48 + n;
#pragma unroll
    for (int reg = 0; reg < 4; ++reg) {
        o[reg * 48 + 0]  = acc0[reg];
        o[reg * 48 + 16] = acc1[reg];
        o[reg * 48 + 32] = acc2[reg];
    }
}

extern "C" void kernel_launch(void* const* d_in, const int* in_sizes, int n_in,
                              void* d_out, int out_size, void* d_ws, size_t ws_size,
                              hipStream_t stream) {
    const int*   ids = (const int*)d_in[0];
    const float* c0  = (const float*)d_in[1];
    const float* c1  = (const float*)d_in[2];
    const float* c2  = (const float*)d_in[3];
    const float* c3  = (const float*)d_in[4];
    const float* c4  = (const float*)d_in[5];
    float* out = (float*)d_out;

    char* ws = (char*)d_ws;
    unsigned short* A2Tb = (unsigned short*)(ws + 0);        // 131072 B
    unsigned short* B3pb = (unsigned short*)(ws + 131072);   // 3145728 B (~3.1 MB total)

    int n_tokens = in_sizes[0];             // 8*512 = 4096

    k_prep<<<2112, 256, 0, stream>>>(c0, c1, c2, c3, c4, A2Tb, B3pb);
    k_main<<<(n_tokens + 3) / 4, 256, 0, stream>>>(ids, A2Tb, B3pb, out, n_tokens);
}